// Round 16
// baseline (446.312 us; speedup 1.0000x reference)
//
#include <hip/hip_runtime.h>
#include <hip/hip_bf16.h>

typedef __attribute__((ext_vector_type(8))) short bf16x8;
typedef __attribute__((ext_vector_type(4))) float f32x4;
typedef __attribute__((ext_vector_type(16))) float f32x16;

#define WAIT_VMCNT(n) asm volatile("s_waitcnt vmcnt(" #n ")" ::: "memory")

__device__ __forceinline__ unsigned short f2b(float f) {
  __hip_bfloat16 h = __float2bfloat16(f);
  return __builtin_bit_cast(unsigned short, h);
}
__device__ __forceinline__ float b2f(unsigned short u) {
  return __bfloat162float(__builtin_bit_cast(__hip_bfloat16, u));
}
// packed f32x2 -> bf16x2 in one instruction (gfx950 v_cvt_pk_bf16_f32, RNE)
__device__ __forceinline__ unsigned int pk2(float a, float b) {
  unsigned int r;
  asm("v_cvt_pk_bf16_f32 %0, %1, %2" : "=v"(r) : "v"(a), "v"(b));
  return r;
}

// async global->LDS, 16B per lane. LDS dest must be linear (uniform base + lane*16).
__device__ __forceinline__ void gld_lds16(const void* g, void* l) {
  __builtin_amdgcn_global_load_lds(
      (const __attribute__((address_space(1))) unsigned int*)g,
      (__attribute__((address_space(3))) unsigned int*)l, 16, 0, 0);
}

// ---------------- fp32 -> bf16 elementwise (x4 vectorized) ----------------
__global__ void convert_kernel(const float* __restrict__ in, unsigned short* __restrict__ out, int n4) {
  int i = blockIdx.x * blockDim.x + threadIdx.x;
  if (i >= n4) return;
  float4 v = ((const float4*)in)[i];
  uint2 o;
  o.x = pk2(v.x, v.y);
  o.y = pk2(v.z, v.w);
  *(uint2*)(out + (size_t)i * 4) = o;
}

// ---------- transpose + convert: in[R][C] f32 -> out[C][R] bf16 ----------
__global__ void transpose_convert_kernel(const float* __restrict__ in, unsigned short* __restrict__ out,
                                         int R, int C) {
  __shared__ float tile[32][33];
  int c0 = blockIdx.x * 32, r0 = blockIdx.y * 32;
  int tx = threadIdx.x, ty = threadIdx.y;
#pragma unroll
  for (int k = 0; k < 32; k += 8)
    tile[ty + k][tx] = in[(size_t)(r0 + ty + k) * C + (c0 + tx)];
  __syncthreads();
#pragma unroll
  for (int k = 0; k < 32; k += 8)
    out[(size_t)(c0 + ty + k) * R + (r0 + tx)] = f2b(tile[tx][ty + k]);
}

// ---------------- RoPE in-place on bf16 buffer [S][heads*128] ----------------
__global__ void rope_kernel(unsigned short* __restrict__ buf, const int* __restrict__ pos,
                            int log2h, int rowstride, float outscale, int total) {
  int idx = blockIdx.x * blockDim.x + threadIdx.x;
  if (idx >= total) return;
  int i = idx & 63;
  int h = (idx >> 6) & ((1 << log2h) - 1);
  int s = idx >> (6 + log2h);
  float inv = expf(-0.14391156831212787f * (float)i);  // 10000^(-i/64)
  float f = (float)pos[s] * inv;
  float sn, cs;
  sincosf(f, &sn, &cs);
  unsigned short* p = buf + (size_t)s * rowstride + (h << 7) + i;
  float x1 = b2f(p[0]);
  float x2 = b2f(p[64]);
  p[0]  = f2b((x1 * cs - x2 * sn) * outscale);
  p[64] = f2b((x2 * cs + x1 * sn) * outscale);
}

// ---------------- GEMM 128x256 tile, BK=64, 8 waves (2M x 4N) ----------------
// TRIPLE-buffered LDS (144KB), ONE raw s_barrier per K-step (gemm_kv-proven schedule):
// barrier -> stage(kt+2) into buffer freed at kt-1 -> ds_read buf[cur] -> MFMA.
// Counted vmcnt(6), never drains lgkm in-loop; waves may slip a full K-tile so the
// 2 waves/SIMD anti-phase. XOR swizzle (16B chunk ^ row&7) on stage-source and ds_read.
// OUT_MODE: 0 = bf16 row-major (ld N); 1 = f32 row-major (ld N).
template <int OUT_MODE>
__global__ __launch_bounds__(512, 2) void gemm_big_kernel(const unsigned short* __restrict__ A,
                                                          const unsigned short* __restrict__ Bt,
                                                          void* __restrict__ Cv,
                                                          int M, int N, int K) {
  constexpr int BM = 128, BN = 256;
  constexpr int MI = BM / 32;           // 4 A fragments per wave
  constexpr int NI = 4;                 // 4 B fragments per wave (WN=64)
  __shared__ unsigned short As[3][BM * 64];  // 48KB
  __shared__ unsigned short Bs[3][BN * 64];  // 96KB

  int tid = threadIdx.x, lane = tid & 63, wave = tid >> 6;
  int wm = wave >> 2, wn = wave & 3;

  // XCD swizzle (nwg % 8 == 0 for all our grids)
  int gx = gridDim.x, nwg = gx * gridDim.y;
  int lin = blockIdx.y * gx + blockIdx.x;
  int swz = (lin & 7) * (nwg >> 3) + (lin >> 3);
  int m0 = (swz / gx) * BM, n0 = (swz % gx) * BN;

  int row0 = tid >> 3, ch = tid & 7;
  const unsigned short* pa0 = A + (size_t)(m0 + row0) * K + ((ch ^ (row0 & 7)) << 3);
  const unsigned short* pb0 = Bt + (size_t)(n0 + row0) * K + ((ch ^ (row0 & 7)) << 3);
  size_t rstep = (size_t)64 * K;

  auto stage = [&](int b, int kt) {
    const unsigned short* a = pa0 + (size_t)kt * 64;
    const unsigned short* bb = pb0 + (size_t)kt * 64;
#pragma unroll
    for (int it = 0; it < 2; ++it)
      gld_lds16(a + it * rstep, (unsigned short*)As[b] + (it * 512 + tid) * 8);
#pragma unroll
    for (int it = 0; it < 4; ++it)
      gld_lds16(bb + it * rstep, (unsigned short*)Bs[b] + (it * 512 + tid) * 8);
  };

  f32x4 acc[MI][NI] = {};

  int nk = K >> 6;
  stage(0, 0);
  stage(1, 1);
  int cur = 0;
  for (int kt = 0; kt < nk; ++kt) {
    if (kt + 1 < nk) WAIT_VMCNT(6); else WAIT_VMCNT(0);
    __builtin_amdgcn_s_barrier();  // buf[cur] staged; all waves done reading buf[(cur+2)%3]
    if (kt + 2 < nk) {
      int b2 = cur + 2; if (b2 >= 3) b2 -= 3;
      stage(b2, kt + 2);           // flies under this K-step's compute
    }

    bf16x8 af[MI][2], bfr[NI][2];
#pragma unroll
    for (int mi = 0; mi < MI; ++mi) {
      int r = wm * (BM / 2) + mi * 16 + (lane & 15);
#pragma unroll
      for (int kk = 0; kk < 2; ++kk)
        af[mi][kk] = *(const bf16x8*)((const char*)As[cur] +
                      r * 128 + (((kk * 4 + (lane >> 4)) ^ (r & 7)) << 4));
    }
#pragma unroll
    for (int ni = 0; ni < NI; ++ni) {
      int r = wn * 64 + ni * 16 + (lane & 15);
#pragma unroll
      for (int kk = 0; kk < 2; ++kk)
        bfr[ni][kk] = *(const bf16x8*)((const char*)Bs[cur] +
                       r * 128 + (((kk * 4 + (lane >> 4)) ^ (r & 7)) << 4));
    }

    __builtin_amdgcn_s_setprio(1);
#pragma unroll
    for (int mi = 0; mi < MI; ++mi)
#pragma unroll
      for (int ni = 0; ni < NI; ++ni)
#pragma unroll
        for (int kk = 0; kk < 2; ++kk)
          acc[mi][ni] = __builtin_amdgcn_mfma_f32_16x16x32_bf16(af[mi][kk], bfr[ni][kk],
                                                                acc[mi][ni], 0, 0, 0);
    __builtin_amdgcn_s_setprio(0);
    cur = (cur == 2) ? 0 : cur + 1;
  }

#pragma unroll
  for (int mi = 0; mi < MI; ++mi) {
#pragma unroll
    for (int ni = 0; ni < NI; ++ni) {
      int col = n0 + wn * 64 + ni * 16 + (lane & 15);
      int rbase = m0 + wm * (BM / 2) + mi * 16 + (lane >> 4) * 4;
#pragma unroll
      for (int j = 0; j < 4; ++j) {
        if (OUT_MODE == 1)
          ((float*)Cv)[(size_t)(rbase + j) * N + col] = acc[mi][ni][j];
        else
          ((unsigned short*)Cv)[(size_t)(rbase + j) * N + col] = f2b(acc[mi][ni][j]);
      }
    }
  }
}

// ---------------- KV GEMM: 128x128 tile, BK=32, 4 waves, 3-buffer (R9-proven) ----------
__global__ __launch_bounds__(256) void gemm_kv_kernel(const unsigned short* __restrict__ A,
                                                      const unsigned short* __restrict__ Bt,
                                                      unsigned short* __restrict__ Kb,
                                                      unsigned short* __restrict__ Vt,
                                                      int K) {
  __shared__ unsigned short As[3][128 * 32];
  __shared__ unsigned short Bs[3][128 * 32];
  int tid = threadIdx.x;
  int lane = tid & 63;
  int wave = tid >> 6;

  int nwg = gridDim.x * gridDim.y;
  int lin = blockIdx.y * gridDim.x + blockIdx.x;
  int cpx = nwg >> 3;
  int swz = (lin & 7) * cpx + (lin >> 3);
  int m0 = (swz / gridDim.x) * 128, n0 = (swz % gridDim.x) * 128;

  int wr = wave >> 1, wc = wave & 1;
  f32x4 acc[4][4] = {};

  int row0 = tid >> 2, cc0 = tid & 3;
  const unsigned short* pa0 = A + (size_t)(m0 + row0) * K + cc0 * 8;
  const unsigned short* pa1 = A + (size_t)(m0 + row0 + 64) * K + cc0 * 8;
  const unsigned short* pb0 = Bt + (size_t)(n0 + row0) * K + cc0 * 8;
  const unsigned short* pb1 = Bt + (size_t)(n0 + row0 + 64) * K + cc0 * 8;

  auto stage = [&](int b, int k0) {
    gld_lds16(pa0 + k0, (unsigned short*)As[b] + tid * 8);
    gld_lds16(pa1 + k0, (unsigned short*)As[b] + (256 + tid) * 8);
    gld_lds16(pb0 + k0, (unsigned short*)Bs[b] + tid * 8);
    gld_lds16(pb1 + k0, (unsigned short*)Bs[b] + (256 + tid) * 8);
  };

  int nk = K >> 5;
  stage(0, 0);
  stage(1, 32);
  int cur = 0;
  for (int ki = 0; ki < nk; ++ki) {
    if (ki + 1 < nk) WAIT_VMCNT(4); else WAIT_VMCNT(0);
    __builtin_amdgcn_s_barrier();
    if (ki + 2 < nk) {
      int b2 = cur + 2; if (b2 >= 3) b2 -= 3;
      stage(b2, (ki + 2) * 32);
    }
    bf16x8 af[4], bfr[4];
#pragma unroll
    for (int mi = 0; mi < 4; ++mi) {
      int r = wr * 64 + mi * 16 + (lane & 15);
      af[mi] = *(const bf16x8*)((const char*)As[cur] + r * 64 + (lane >> 4) * 16);
    }
#pragma unroll
    for (int ni = 0; ni < 4; ++ni) {
      int r = wc * 64 + ni * 16 + (lane & 15);
      bfr[ni] = *(const bf16x8*)((const char*)Bs[cur] + r * 64 + (lane >> 4) * 16);
    }
#pragma unroll
    for (int mi = 0; mi < 4; ++mi)
#pragma unroll
      for (int ni = 0; ni < 4; ++ni)
        acc[mi][ni] = __builtin_amdgcn_mfma_f32_16x16x32_bf16(af[mi], bfr[ni], acc[mi][ni], 0, 0, 0);
    cur = (cur == 2) ? 0 : cur + 1;
  }

#pragma unroll
  for (int mi = 0; mi < 4; ++mi) {
#pragma unroll
    for (int ni = 0; ni < 4; ++ni) {
      int col = n0 + wc * 64 + ni * 16 + (lane & 15);
      int rbase = m0 + wr * 64 + mi * 16 + (lane >> 4) * 4;
      if (col < 512) {
#pragma unroll
        for (int j = 0; j < 4; ++j)
          Kb[(size_t)(rbase + j) * 512 + col] = f2b(acc[mi][ni][j]);
      } else {
        int cv = col - 512;
        int hk = cv >> 7, d = cv & 127;
        uint2 u;
        u.x = pk2(acc[mi][ni][0], acc[mi][ni][1]);
        u.y = pk2(acc[mi][ni][2], acc[mi][ni][3]);
        size_t addr = (size_t)hk * 524288 + (size_t)(rbase >> 6) * 8192 + d * 64 + (rbase & 63);
        *(uint2*)(Vt + addr) = u;
      }
    }
  }
}

// ---------------- Flash attention (causal, GQA 32q/4kv, D=128), 32x32 MFMA ----------------
// R15 config VERBATIM (best known: 204.6us): quad-buffered K/V, ONE barrier per tile PAIR.
__global__ __launch_bounds__(512) void attn_kernel(const unsigned short* __restrict__ Q,
                                                   const unsigned short* __restrict__ Kp,
                                                   const unsigned short* __restrict__ Vt,
                                                   unsigned short* __restrict__ O) {
  __shared__ unsigned short k_lds[4][64 * 128];   // 64KB
  __shared__ unsigned short vt_lds[4][128 * 64];  // 64KB

  int lin = blockIdx.y * 8 + blockIdx.x;          // grid (8, 32) = 256 blocks
  int h = (lin & 7) * 4 + (lin >> 6);             // 4 heads per XCD
  int xpair = (lin >> 3) & 7;
  int hk = h >> 3;
  int tid = threadIdx.x, lane = tid & 63, wave = tid >> 6;
  int l31 = lane & 31, hi = lane >> 5;

  // staging sources (pre-swizzled, per-thread constant)
  int krow0 = tid >> 4, kch = tid & 15;
  int krow1 = krow0 + 32;
  const unsigned short* kp0 = Kp + (hk << 7) + (size_t)krow0 * 512 + ((kch ^ (krow0 & 15)) << 3);
  const unsigned short* kp1 = Kp + (hk << 7) + (size_t)krow1 * 512 + ((kch ^ (krow1 & 15)) << 3);
  int vd0 = tid >> 3, vsc = tid & 7;
  int vd1 = vd0 + 64;
  const unsigned short* vp0 = Vt + (size_t)hk * 524288 + vd0 * 64 + ((vsc ^ (vd0 & 7)) << 3);
  const unsigned short* vp1 = Vt + (size_t)hk * 524288 + vd1 * 64 + ((vsc ^ (vd1 & 7)) << 3);

  auto stage_tile = [&](int b, int t) {
    gld_lds16(kp0 + (size_t)t * 32768, (unsigned short*)k_lds[b] + tid * 8);
    gld_lds16(kp1 + (size_t)t * 32768, (unsigned short*)k_lds[b] + (512 + tid) * 8);
    gld_lds16(vp0 + (size_t)t * 8192, (unsigned short*)vt_lds[b] + tid * 8);
    gld_lds16(vp1 + (size_t)t * 8192, (unsigned short*)vt_lds[b] + (512 + tid) * 8);
  };

  for (int pass = 0; pass < 2; ++pass) {
    int SB = pass ? (15 - xpair) : xpair;
    int qt = SB * 8 + wave;         // 32-row q-tile index, 0..127
    int qrow = qt * 32 + l31;
    int tdiag = qt >> 1;            // participate iff t0 <= tdiag; mask iff t0 == tdiag
    int ntiles = 4 * SB + 4;        // always even, >= 4
    int npairs = ntiles >> 1;

    bf16x8 qf[8];
#pragma unroll
    for (int kk = 0; kk < 8; ++kk)
      qf[kk] = *(const bf16x8*)(Q + (size_t)qrow * 4096 + (h << 7) + kk * 16 + hi * 8);

    f32x16 o_acc[4] = {};
    float m_run = -3.0e38f, l_run = 0.0f;

    __syncthreads();  // prior pass's epilogue scratch reads done before restaging
    stage_tile(0, 0);
    stage_tile(1, 1);
    for (int p = 0; p < npairs; ++p) {
      WAIT_VMCNT(0);                 // pair p staged (issued a full pair-compute ago)
      __builtin_amdgcn_s_barrier();  // all waves done reading the pair staged 2 iters ago
      if (2 * p + 2 < ntiles) {
        stage_tile((2 * p + 2) & 3, 2 * p + 2);
        stage_tile((2 * p + 3) & 3, 2 * p + 3);
      }

#pragma unroll
      for (int half = 0; half < 2; ++half) {
        int t0 = 2 * p + half;
        int cur = t0 & 3;
        if (t0 > tdiag) continue;
        int s0 = t0 * 64;
        // ---- S^T = K * Q^T (32x32x16), sacc[t] = s-subtile t*32 ----
        f32x16 sacc[2] = {};
        __builtin_amdgcn_s_setprio(1);
#pragma unroll
        for (int kk = 0; kk < 8; ++kk) {
#pragma unroll
          for (int t = 0; t < 2; ++t) {
            bf16x8 kf = *(const bf16x8*)((const char*)k_lds[cur] +
                         ((t * 32 + l31) * 256 + (((kk * 2 + hi) ^ (l31 & 15)) << 4)));
            sacc[t] = __builtin_amdgcn_mfma_f32_32x32x16_bf16(kf, qf[kk], sacc[t], 0, 0, 0);
          }
        }
        __builtin_amdgcn_s_setprio(0);

        // ---- online softmax (exp2 domain), fully lane-local per q ----
        float mx = -3.0e38f;
        if (t0 == tdiag) {
#pragma unroll
          for (int t = 0; t < 2; ++t)
#pragma unroll
            for (int r = 0; r < 16; ++r) {
              int sg = s0 + t * 32 + (r & 3) + 8 * (r >> 2) + 4 * hi;
              float v = sacc[t][r];
              v = (sg <= qrow) ? v : -3.0e38f;
              sacc[t][r] = v;
              mx = fmaxf(mx, v);
            }
        } else {
#pragma unroll
          for (int t = 0; t < 2; ++t)
#pragma unroll
            for (int r = 0; r < 16; ++r)
              mx = fmaxf(mx, sacc[t][r]);
        }
        mx = fmaxf(mx, __shfl_xor(mx, 32));
        // defer-max: only rescale when running max grew by > 8*log2(e)
        if (!__all(mx <= m_run + 11.5416f)) {
          float m_new = fmaxf(m_run, mx);
          float corr = exp2f(m_run - m_new);
          l_run *= corr;
#pragma unroll
          for (int ds = 0; ds < 4; ++ds)
#pragma unroll
            for (int r = 0; r < 16; ++r) o_acc[ds][r] *= corr;
          m_run = m_new;
        }
        float rsum = 0.0f;
#pragma unroll
        for (int t = 0; t < 2; ++t)
#pragma unroll
          for (int r = 0; r < 16; ++r) {
            float e = exp2f(sacc[t][r] - m_run);
            sacc[t][r] = e;
            rsum += e;
          }
        l_run += rsum + __shfl_xor(rsum, 32);

        // ---- build PV B-fragments in-register (cvt_pk + lane^32 swap) ----
        bf16x8 pb[4];
#pragma unroll
        for (int kk = 0; kk < 4; ++kk) {
          int t = kk >> 1;
          int b0 = (kk & 1) * 8;
          unsigned int a0 = pk2(sacc[t][b0 + 0], sacc[t][b0 + 1]);
          unsigned int a1 = pk2(sacc[t][b0 + 2], sacc[t][b0 + 3]);
          unsigned int c0 = pk2(sacc[t][b0 + 4], sacc[t][b0 + 5]);
          unsigned int c1 = pk2(sacc[t][b0 + 6], sacc[t][b0 + 7]);
          unsigned int snd0 = hi ? a0 : c0, snd1 = hi ? a1 : c1;
          unsigned int rcv0 = __shfl_xor(snd0, 32);
          unsigned int rcv1 = __shfl_xor(snd1, 32);
          unsigned int own0 = hi ? c0 : a0, own1 = hi ? c1 : a1;
          uint4 w;
          w.x = hi ? rcv0 : own0;
          w.y = hi ? rcv1 : own1;
          w.z = hi ? own0 : rcv0;
          w.w = hi ? own1 : rcv1;
          pb[kk] = __builtin_bit_cast(bf16x8, w);
        }

        // ---- PV: O^T[d][q] += Vt * P^T ----
        __builtin_amdgcn_s_setprio(1);
#pragma unroll
        for (int ds = 0; ds < 4; ++ds) {
#pragma unroll
          for (int kk = 0; kk < 4; ++kk) {
            bf16x8 vf = *(const bf16x8*)((const char*)vt_lds[cur] +
                         ((ds * 32 + l31) * 128 + (((kk * 2 + hi) ^ (l31 & 7)) << 4)));
            o_acc[ds] = __builtin_amdgcn_mfma_f32_32x32x16_bf16(vf, pb[kk], o_acc[ds], 0, 0, 0);
          }
        }
        __builtin_amdgcn_s_setprio(0);
      }
    }

    __syncthreads();  // all waves done with final tiles before scratch overlays k_lds

    // ---- epilogue: transpose O^T->O via per-wave LDS scratch, store bf16 ----
    float inv_l = 1.0f / l_run;
    char* scr = (char*)k_lds + wave * 2304;  // 32 rows x 72B, wave-private
#pragma unroll
    for (int ds = 0; ds < 4; ++ds) {
#pragma unroll
      for (int rp = 0; rp < 8; ++rp) {
        int r = rp * 2;
        int d_loc = (r & 3) + 8 * (r >> 2) + 4 * hi;  // even; pair covers d_loc, d_loc+1
        *(unsigned int*)(scr + l31 * 72 + ((d_loc >> 1) << 2)) =
            pk2(o_acc[ds][r] * inv_l, o_acc[ds][r + 1] * inv_l);
      }
      uint2 u0 = *(uint2*)(scr + l31 * 72 + hi * 32 + 0);
      uint2 u1 = *(uint2*)(scr + l31 * 72 + hi * 32 + 8);
      uint2 u2 = *(uint2*)(scr + l31 * 72 + hi * 32 + 16);
      uint2 u3 = *(uint2*)(scr + l31 * 72 + hi * 32 + 24);
      unsigned short* op = O + (size_t)qrow * 4096 + (h << 7) + ds * 32 + hi * 16;
      uint4 s0v; s0v.x = u0.x; s0v.y = u0.y; s0v.z = u1.x; s0v.w = u1.y;
      uint4 s1v; s1v.x = u2.x; s1v.y = u2.y; s1v.z = u3.x; s1v.w = u3.y;
      *(uint4*)(op) = s0v;
      *(uint4*)(op + 8) = s1v;
    }
  }
}

extern "C" void kernel_launch(void* const* d_in, const int* in_sizes, int n_in,
                              void* d_out, int out_size, void* d_ws, size_t ws_size,
                              hipStream_t stream) {
  const float* X  = (const float*)d_in[0];
  const float* Wq = (const float*)d_in[1];
  const float* Wk = (const float*)d_in[2];
  const float* Wv = (const float*)d_in[3];
  const float* Wo = (const float*)d_in[4];
  const int* pos  = (const int*)d_in[5];
  // d_in[6] attention_mask: causal tril -- enforced analytically in attn_kernel.

  const size_t MB = 1u << 20;
  char* w = (char*)d_ws;
  // Wkt/Wvt contiguous: a [1024][2048] bf16 block for the KV GEMM.
  unsigned short* Xb  = (unsigned short*)(w + 0 * MB);    // [4096][2048] 16MB
  unsigned short* Wqt = (unsigned short*)(w + 16 * MB);   // [4096][2048] 16MB
  unsigned short* Wkt = (unsigned short*)(w + 32 * MB);   // [512][2048]   2MB
  unsigned short* Wvt = (unsigned short*)(w + 34 * MB);   // [512][2048]   2MB
  unsigned short* Wot = (unsigned short*)(w + 36 * MB);   // [2048][4096] 16MB
  unsigned short* Qb  = (unsigned short*)(w + 52 * MB);   // [4096][4096] 32MB
  unsigned short* Kb  = (unsigned short*)(w + 84 * MB);   // [4096][512]   4MB
  unsigned short* Vtb = (unsigned short*)(w + 88 * MB);   // [4 hk][64 st][128 d][64 s] 4MB
  unsigned short* Ob  = (unsigned short*)(w + 92 * MB);   // [4096][4096] 32MB

  // 1) dtype conversion + weight transposes
  convert_kernel<<<8192, 256, 0, stream>>>(X, Xb, 4096 * 2048 / 4);
  transpose_convert_kernel<<<dim3(128, 64), dim3(32, 8), 0, stream>>>(Wq, Wqt, 2048, 4096);
  transpose_convert_kernel<<<dim3(16, 64),  dim3(32, 8), 0, stream>>>(Wk, Wkt, 2048, 512);
  transpose_convert_kernel<<<dim3(16, 64),  dim3(32, 8), 0, stream>>>(Wv, Wvt, 2048, 512);
  transpose_convert_kernel<<<dim3(64, 128), dim3(32, 8), 0, stream>>>(Wo, Wot, 4096, 2048);

  // 2a) Q projection: 128x256 tiles, 3-buffer single-barrier, grid 16x32 = 512 blocks
  gemm_big_kernel<0><<<dim3(16, 32), 512, 0, stream>>>(Xb, Wqt, Qb, 4096, 4096, 2048);
  // 2b) KV projection: 128x128 tiles, grid 256 blocks, 3 blocks/CU (V written tiled)
  gemm_kv_kernel<<<dim3(8, 32), 256, 0, stream>>>(Xb, Wkt, Kb, Vtb, 2048);

  // 3) RoPE (Q gets 1/sqrt(128)*log2(e) folded in for exp2-domain softmax)
  rope_kernel<<<(4096 * 32 * 64) / 256, 256, 0, stream>>>(Qb, pos, 5, 4096, 0.12752792534390558f, 4096 * 32 * 64);
  rope_kernel<<<(4096 * 4 * 64) / 256,  256, 0, stream>>>(Kb, pos, 2, 512, 1.0f, 4096 * 4 * 64);

  // 4) causal flash attention (R15 config verbatim)
  attn_kernel<<<dim3(8, 32), 512, 0, stream>>>(Qb, Kb, Vtb, Ob);

  // 5) output projection -> fp32 d_out, 128x256 tiles, 3-buffer single-barrier
  gemm_big_kernel<1><<<dim3(8, 32), 512, 0, stream>>>(Ob, Wot, d_out, 4096, 2048, 4096);
}

// Round 17
// 408.135 us; speedup vs baseline: 1.0935x; 1.0935x over previous
//
#include <hip/hip_runtime.h>
#include <hip/hip_bf16.h>

typedef __attribute__((ext_vector_type(8))) short bf16x8;
typedef __attribute__((ext_vector_type(4))) float f32x4;
typedef __attribute__((ext_vector_type(16))) float f32x16;

#define WAIT_VMCNT(n) asm volatile("s_waitcnt vmcnt(" #n ")" ::: "memory")
#define WAIT_LGKM0()  asm volatile("s_waitcnt lgkmcnt(0)" ::: "memory")

__device__ __forceinline__ unsigned short f2b(float f) {
  __hip_bfloat16 h = __float2bfloat16(f);
  return __builtin_bit_cast(unsigned short, h);
}
__device__ __forceinline__ float b2f(unsigned short u) {
  return __bfloat162float(__builtin_bit_cast(__hip_bfloat16, u));
}
// packed f32x2 -> bf16x2 in one instruction (gfx950 v_cvt_pk_bf16_f32, RNE)
__device__ __forceinline__ unsigned int pk2(float a, float b) {
  unsigned int r;
  asm("v_cvt_pk_bf16_f32 %0, %1, %2" : "=v"(r) : "v"(a), "v"(b));
  return r;
}

// async global->LDS, 16B per lane. LDS dest must be linear (uniform base + lane*16).
__device__ __forceinline__ void gld_lds16(const void* g, void* l) {
  __builtin_amdgcn_global_load_lds(
      (const __attribute__((address_space(1))) unsigned int*)g,
      (__attribute__((address_space(3))) unsigned int*)l, 16, 0, 0);
}

// ---------------- fp32 -> bf16 elementwise (x4 vectorized) ----------------
__global__ void convert_kernel(const float* __restrict__ in, unsigned short* __restrict__ out, int n4) {
  int i = blockIdx.x * blockDim.x + threadIdx.x;
  if (i >= n4) return;
  float4 v = ((const float4*)in)[i];
  uint2 o;
  o.x = pk2(v.x, v.y);
  o.y = pk2(v.z, v.w);
  *(uint2*)(out + (size_t)i * 4) = o;
}

// ---------- transpose + convert: in[R][C] f32 -> out[C][R] bf16 ----------
__global__ void transpose_convert_kernel(const float* __restrict__ in, unsigned short* __restrict__ out,
                                         int R, int C) {
  __shared__ float tile[32][33];
  int c0 = blockIdx.x * 32, r0 = blockIdx.y * 32;
  int tx = threadIdx.x, ty = threadIdx.y;
#pragma unroll
  for (int k = 0; k < 32; k += 8)
    tile[ty + k][tx] = in[(size_t)(r0 + ty + k) * C + (c0 + tx)];
  __syncthreads();
#pragma unroll
  for (int k = 0; k < 32; k += 8)
    out[(size_t)(c0 + ty + k) * R + (r0 + tx)] = f2b(tile[tx][ty + k]);
}

// ---------------- RoPE in-place on bf16 buffer [S][heads*128] ----------------
__global__ void rope_kernel(unsigned short* __restrict__ buf, const int* __restrict__ pos,
                            int log2h, int rowstride, float outscale, int total) {
  int idx = blockIdx.x * blockDim.x + threadIdx.x;
  if (idx >= total) return;
  int i = idx & 63;
  int h = (idx >> 6) & ((1 << log2h) - 1);
  int s = idx >> (6 + log2h);
  float inv = expf(-0.14391156831212787f * (float)i);  // 10000^(-i/64)
  float f = (float)pos[s] * inv;
  float sn, cs;
  sincosf(f, &sn, &cs);
  unsigned short* p = buf + (size_t)s * rowstride + (h << 7) + i;
  float x1 = b2f(p[0]);
  float x2 = b2f(p[64]);
  p[0]  = f2b((x1 * cs - x2 * sn) * outscale);
  p[64] = f2b((x2 * cs + x1 * sn) * outscale);
}

// ---------------- GEMM BMxBN tile, BK=64, 8 waves (2M x 4N) ----------------
// All fragments ds_read into registers in one burst -> lgkm0 + barrier frees the whole
// buffer -> tile kt+2 staged under the MFMA burst. Counted vmcnt, never drains in-loop.
// LDS rows are 128B -> XOR swizzle (16B chunk ^ row&7) on stage-source and ds_read.
// OUT_MODE: 0 = bf16 row-major (ld N); 1 = f32 row-major (ld N).
template <int OUT_MODE, int BM, int BN>
__global__ __launch_bounds__(512, 2) void gemm_big_kernel(const unsigned short* __restrict__ A,
                                                          const unsigned short* __restrict__ Bt,
                                                          void* __restrict__ Cv,
                                                          int M, int N, int K) {
  constexpr int MI = BM / 32;           // A fragments per wave
  constexpr int WN = BN / 4;            // per-wave N width
  constexpr int NI = WN / 16;           // B fragments per wave
  constexpr int A_IT = BM / 64;         // A staging chunks per thread
  constexpr int B_IT = BN / 64;         // B staging chunks per thread
  __shared__ unsigned short As[2][BM * 64];
  __shared__ unsigned short Bs[2][BN * 64];

  int tid = threadIdx.x, lane = tid & 63, wave = tid >> 6;
  int wm = wave >> 2, wn = wave & 3;

  // XCD swizzle (nwg % 8 == 0 for all our grids)
  int gx = gridDim.x, nwg = gx * gridDim.y;
  int lin = blockIdx.y * gx + blockIdx.x;
  int swz = (lin & 7) * (nwg >> 3) + (lin >> 3);
  int m0 = (swz / gx) * BM, n0 = (swz % gx) * BN;

  int row0 = tid >> 3, ch = tid & 7;
  const unsigned short* pa0 = A + (size_t)(m0 + row0) * K + ((ch ^ (row0 & 7)) << 3);
  const unsigned short* pb0 = Bt + (size_t)(n0 + row0) * K + ((ch ^ (row0 & 7)) << 3);
  size_t rstep = (size_t)64 * K;

  auto stage = [&](int b, int kt) {
    const unsigned short* a = pa0 + (size_t)kt * 64;
    const unsigned short* bb = pb0 + (size_t)kt * 64;
#pragma unroll
    for (int it = 0; it < A_IT; ++it)
      gld_lds16(a + it * rstep, (unsigned short*)As[b] + (it * 512 + tid) * 8);
#pragma unroll
    for (int it = 0; it < B_IT; ++it)
      gld_lds16(bb + it * rstep, (unsigned short*)Bs[b] + (it * 512 + tid) * 8);
  };

  f32x4 acc[MI][NI] = {};

  int nk = K >> 6;
  stage(0, 0);
  stage(1, 1);
  for (int kt = 0; kt < nk; ++kt) {
    int cur = kt & 1;
    if (kt + 1 < nk) {
      if constexpr (A_IT + B_IT == 8) WAIT_VMCNT(8);
      else if constexpr (A_IT + B_IT == 6) WAIT_VMCNT(6);
      else WAIT_VMCNT(4);
    } else {
      WAIT_VMCNT(0);
    }
    __builtin_amdgcn_s_barrier();  // buf[cur] staged by all waves

    bf16x8 af[MI][2], bfr[NI][2];
#pragma unroll
    for (int mi = 0; mi < MI; ++mi) {
      int r = wm * (BM / 2) + mi * 16 + (lane & 15);
#pragma unroll
      for (int kk = 0; kk < 2; ++kk)
        af[mi][kk] = *(const bf16x8*)((const char*)As[cur] +
                      r * 128 + (((kk * 4 + (lane >> 4)) ^ (r & 7)) << 4));
    }
#pragma unroll
    for (int ni = 0; ni < NI; ++ni) {
      int r = wn * WN + ni * 16 + (lane & 15);
#pragma unroll
      for (int kk = 0; kk < 2; ++kk)
        bfr[ni][kk] = *(const bf16x8*)((const char*)Bs[cur] +
                       r * 128 + (((kk * 4 + (lane >> 4)) ^ (r & 7)) << 4));
    }
    WAIT_LGKM0();                   // my reads landed in registers
    __builtin_amdgcn_s_barrier();   // all waves done reading buf[cur]
    if (kt + 2 < nk) stage(cur, kt + 2);  // refill freed buffer under the MFMAs

    __builtin_amdgcn_s_setprio(1);
#pragma unroll
    for (int mi = 0; mi < MI; ++mi)
#pragma unroll
      for (int ni = 0; ni < NI; ++ni)
#pragma unroll
        for (int kk = 0; kk < 2; ++kk)
          acc[mi][ni] = __builtin_amdgcn_mfma_f32_16x16x32_bf16(af[mi][kk], bfr[ni][kk],
                                                                acc[mi][ni], 0, 0, 0);
    __builtin_amdgcn_s_setprio(0);
  }

#pragma unroll
  for (int mi = 0; mi < MI; ++mi) {
#pragma unroll
    for (int ni = 0; ni < NI; ++ni) {
      int col = n0 + wn * WN + ni * 16 + (lane & 15);
      int rbase = m0 + wm * (BM / 2) + mi * 16 + (lane >> 4) * 4;
#pragma unroll
      for (int j = 0; j < 4; ++j) {
        if (OUT_MODE == 1)
          ((float*)Cv)[(size_t)(rbase + j) * N + col] = acc[mi][ni][j];
        else
          ((unsigned short*)Cv)[(size_t)(rbase + j) * N + col] = f2b(acc[mi][ni][j]);
      }
    }
  }
}

// ---------------- KV GEMM: 128x128 tile, BK=32, 4 waves, 3-buffer (R9-proven) ----------
__global__ __launch_bounds__(256) void gemm_kv_kernel(const unsigned short* __restrict__ A,
                                                      const unsigned short* __restrict__ Bt,
                                                      unsigned short* __restrict__ Kb,
                                                      unsigned short* __restrict__ Vt,
                                                      int K) {
  __shared__ unsigned short As[3][128 * 32];
  __shared__ unsigned short Bs[3][128 * 32];
  int tid = threadIdx.x;
  int lane = tid & 63;
  int wave = tid >> 6;

  int nwg = gridDim.x * gridDim.y;
  int lin = blockIdx.y * gridDim.x + blockIdx.x;
  int cpx = nwg >> 3;
  int swz = (lin & 7) * cpx + (lin >> 3);
  int m0 = (swz / gridDim.x) * 128, n0 = (swz % gridDim.x) * 128;

  int wr = wave >> 1, wc = wave & 1;
  f32x4 acc[4][4] = {};

  int row0 = tid >> 2, cc0 = tid & 3;
  const unsigned short* pa0 = A + (size_t)(m0 + row0) * K + cc0 * 8;
  const unsigned short* pa1 = A + (size_t)(m0 + row0 + 64) * K + cc0 * 8;
  const unsigned short* pb0 = Bt + (size_t)(n0 + row0) * K + cc0 * 8;
  const unsigned short* pb1 = Bt + (size_t)(n0 + row0 + 64) * K + cc0 * 8;

  auto stage = [&](int b, int k0) {
    gld_lds16(pa0 + k0, (unsigned short*)As[b] + tid * 8);
    gld_lds16(pa1 + k0, (unsigned short*)As[b] + (256 + tid) * 8);
    gld_lds16(pb0 + k0, (unsigned short*)Bs[b] + tid * 8);
    gld_lds16(pb1 + k0, (unsigned short*)Bs[b] + (256 + tid) * 8);
  };

  int nk = K >> 5;
  stage(0, 0);
  stage(1, 32);
  int cur = 0;
  for (int ki = 0; ki < nk; ++ki) {
    if (ki + 1 < nk) WAIT_VMCNT(4); else WAIT_VMCNT(0);
    __builtin_amdgcn_s_barrier();
    if (ki + 2 < nk) {
      int b2 = cur + 2; if (b2 >= 3) b2 -= 3;
      stage(b2, (ki + 2) * 32);
    }
    bf16x8 af[4], bfr[4];
#pragma unroll
    for (int mi = 0; mi < 4; ++mi) {
      int r = wr * 64 + mi * 16 + (lane & 15);
      af[mi] = *(const bf16x8*)((const char*)As[cur] + r * 64 + (lane >> 4) * 16);
    }
#pragma unroll
    for (int ni = 0; ni < 4; ++ni) {
      int r = wc * 64 + ni * 16 + (lane & 15);
      bfr[ni] = *(const bf16x8*)((const char*)Bs[cur] + r * 64 + (lane >> 4) * 16);
    }
#pragma unroll
    for (int mi = 0; mi < 4; ++mi)
#pragma unroll
      for (int ni = 0; ni < 4; ++ni)
        acc[mi][ni] = __builtin_amdgcn_mfma_f32_16x16x32_bf16(af[mi], bfr[ni], acc[mi][ni], 0, 0, 0);
    cur = (cur == 2) ? 0 : cur + 1;
  }

#pragma unroll
  for (int mi = 0; mi < 4; ++mi) {
#pragma unroll
    for (int ni = 0; ni < 4; ++ni) {
      int col = n0 + wc * 64 + ni * 16 + (lane & 15);
      int rbase = m0 + wr * 64 + mi * 16 + (lane >> 4) * 4;
      if (col < 512) {
#pragma unroll
        for (int j = 0; j < 4; ++j)
          Kb[(size_t)(rbase + j) * 512 + col] = f2b(acc[mi][ni][j]);
      } else {
        int cv = col - 512;
        int hk = cv >> 7, d = cv & 127;
        uint2 u;
        u.x = pk2(acc[mi][ni][0], acc[mi][ni][1]);
        u.y = pk2(acc[mi][ni][2], acc[mi][ni][3]);
        size_t addr = (size_t)hk * 524288 + (size_t)(rbase >> 6) * 8192 + d * 64 + (rbase & 63);
        *(uint2*)(Vt + addr) = u;
      }
    }
  }
}

// ---------------- Flash attention (causal, GQA 32q/4kv, D=128), 32x32 MFMA ----------------
// R15 config VERBATIM (best known: 204.6us): quad-buffered K/V, ONE barrier per tile PAIR.
__global__ __launch_bounds__(512) void attn_kernel(const unsigned short* __restrict__ Q,
                                                   const unsigned short* __restrict__ Kp,
                                                   const unsigned short* __restrict__ Vt,
                                                   unsigned short* __restrict__ O) {
  __shared__ unsigned short k_lds[4][64 * 128];   // 64KB
  __shared__ unsigned short vt_lds[4][128 * 64];  // 64KB

  int lin = blockIdx.y * 8 + blockIdx.x;          // grid (8, 32) = 256 blocks
  int h = (lin & 7) * 4 + (lin >> 6);             // 4 heads per XCD
  int xpair = (lin >> 3) & 7;
  int hk = h >> 3;
  int tid = threadIdx.x, lane = tid & 63, wave = tid >> 6;
  int l31 = lane & 31, hi = lane >> 5;

  // staging sources (pre-swizzled, per-thread constant)
  int krow0 = tid >> 4, kch = tid & 15;
  int krow1 = krow0 + 32;
  const unsigned short* kp0 = Kp + (hk << 7) + (size_t)krow0 * 512 + ((kch ^ (krow0 & 15)) << 3);
  const unsigned short* kp1 = Kp + (hk << 7) + (size_t)krow1 * 512 + ((kch ^ (krow1 & 15)) << 3);
  int vd0 = tid >> 3, vsc = tid & 7;
  int vd1 = vd0 + 64;
  const unsigned short* vp0 = Vt + (size_t)hk * 524288 + vd0 * 64 + ((vsc ^ (vd0 & 7)) << 3);
  const unsigned short* vp1 = Vt + (size_t)hk * 524288 + vd1 * 64 + ((vsc ^ (vd1 & 7)) << 3);

  auto stage_tile = [&](int b, int t) {
    gld_lds16(kp0 + (size_t)t * 32768, (unsigned short*)k_lds[b] + tid * 8);
    gld_lds16(kp1 + (size_t)t * 32768, (unsigned short*)k_lds[b] + (512 + tid) * 8);
    gld_lds16(vp0 + (size_t)t * 8192, (unsigned short*)vt_lds[b] + tid * 8);
    gld_lds16(vp1 + (size_t)t * 8192, (unsigned short*)vt_lds[b] + (512 + tid) * 8);
  };

  for (int pass = 0; pass < 2; ++pass) {
    int SB = pass ? (15 - xpair) : xpair;
    int qt = SB * 8 + wave;         // 32-row q-tile index, 0..127
    int qrow = qt * 32 + l31;
    int tdiag = qt >> 1;            // participate iff t0 <= tdiag; mask iff t0 == tdiag
    int ntiles = 4 * SB + 4;        // always even, >= 4
    int npairs = ntiles >> 1;

    bf16x8 qf[8];
#pragma unroll
    for (int kk = 0; kk < 8; ++kk)
      qf[kk] = *(const bf16x8*)(Q + (size_t)qrow * 4096 + (h << 7) + kk * 16 + hi * 8);

    f32x16 o_acc[4] = {};
    float m_run = -3.0e38f, l_run = 0.0f;

    __syncthreads();  // prior pass's epilogue scratch reads done before restaging
    stage_tile(0, 0);
    stage_tile(1, 1);
    for (int p = 0; p < npairs; ++p) {
      WAIT_VMCNT(0);                 // pair p staged (issued a full pair-compute ago)
      __builtin_amdgcn_s_barrier();  // all waves done reading the pair staged 2 iters ago
      if (2 * p + 2 < ntiles) {
        stage_tile((2 * p + 2) & 3, 2 * p + 2);
        stage_tile((2 * p + 3) & 3, 2 * p + 3);
      }

#pragma unroll
      for (int half = 0; half < 2; ++half) {
        int t0 = 2 * p + half;
        int cur = t0 & 3;
        if (t0 > tdiag) continue;
        int s0 = t0 * 64;
        // ---- S^T = K * Q^T (32x32x16), sacc[t] = s-subtile t*32 ----
        f32x16 sacc[2] = {};
        __builtin_amdgcn_s_setprio(1);
#pragma unroll
        for (int kk = 0; kk < 8; ++kk) {
#pragma unroll
          for (int t = 0; t < 2; ++t) {
            bf16x8 kf = *(const bf16x8*)((const char*)k_lds[cur] +
                         ((t * 32 + l31) * 256 + (((kk * 2 + hi) ^ (l31 & 15)) << 4)));
            sacc[t] = __builtin_amdgcn_mfma_f32_32x32x16_bf16(kf, qf[kk], sacc[t], 0, 0, 0);
          }
        }
        __builtin_amdgcn_s_setprio(0);

        // ---- online softmax (exp2 domain), fully lane-local per q ----
        float mx = -3.0e38f;
        if (t0 == tdiag) {
#pragma unroll
          for (int t = 0; t < 2; ++t)
#pragma unroll
            for (int r = 0; r < 16; ++r) {
              int sg = s0 + t * 32 + (r & 3) + 8 * (r >> 2) + 4 * hi;
              float v = sacc[t][r];
              v = (sg <= qrow) ? v : -3.0e38f;
              sacc[t][r] = v;
              mx = fmaxf(mx, v);
            }
        } else {
#pragma unroll
          for (int t = 0; t < 2; ++t)
#pragma unroll
            for (int r = 0; r < 16; ++r)
              mx = fmaxf(mx, sacc[t][r]);
        }
        mx = fmaxf(mx, __shfl_xor(mx, 32));
        // defer-max: only rescale when running max grew by > 8*log2(e)
        if (!__all(mx <= m_run + 11.5416f)) {
          float m_new = fmaxf(m_run, mx);
          float corr = exp2f(m_run - m_new);
          l_run *= corr;
#pragma unroll
          for (int ds = 0; ds < 4; ++ds)
#pragma unroll
            for (int r = 0; r < 16; ++r) o_acc[ds][r] *= corr;
          m_run = m_new;
        }
        float rsum = 0.0f;
#pragma unroll
        for (int t = 0; t < 2; ++t)
#pragma unroll
          for (int r = 0; r < 16; ++r) {
            float e = exp2f(sacc[t][r] - m_run);
            sacc[t][r] = e;
            rsum += e;
          }
        l_run += rsum + __shfl_xor(rsum, 32);

        // ---- build PV B-fragments in-register (cvt_pk + lane^32 swap) ----
        bf16x8 pb[4];
#pragma unroll
        for (int kk = 0; kk < 4; ++kk) {
          int t = kk >> 1;
          int b0 = (kk & 1) * 8;
          unsigned int a0 = pk2(sacc[t][b0 + 0], sacc[t][b0 + 1]);
          unsigned int a1 = pk2(sacc[t][b0 + 2], sacc[t][b0 + 3]);
          unsigned int c0 = pk2(sacc[t][b0 + 4], sacc[t][b0 + 5]);
          unsigned int c1 = pk2(sacc[t][b0 + 6], sacc[t][b0 + 7]);
          unsigned int snd0 = hi ? a0 : c0, snd1 = hi ? a1 : c1;
          unsigned int rcv0 = __shfl_xor(snd0, 32);
          unsigned int rcv1 = __shfl_xor(snd1, 32);
          unsigned int own0 = hi ? c0 : a0, own1 = hi ? c1 : a1;
          uint4 w;
          w.x = hi ? rcv0 : own0;
          w.y = hi ? rcv1 : own1;
          w.z = hi ? own0 : rcv0;
          w.w = hi ? own1 : rcv1;
          pb[kk] = __builtin_bit_cast(bf16x8, w);
        }

        // ---- PV: O^T[d][q] += Vt * P^T ----
        __builtin_amdgcn_s_setprio(1);
#pragma unroll
        for (int ds = 0; ds < 4; ++ds) {
#pragma unroll
          for (int kk = 0; kk < 4; ++kk) {
            bf16x8 vf = *(const bf16x8*)((const char*)vt_lds[cur] +
                         ((ds * 32 + l31) * 128 + (((kk * 2 + hi) ^ (l31 & 7)) << 4)));
            o_acc[ds] = __builtin_amdgcn_mfma_f32_32x32x16_bf16(vf, pb[kk], o_acc[ds], 0, 0, 0);
          }
        }
        __builtin_amdgcn_s_setprio(0);
      }
    }

    __syncthreads();  // all waves done with final tiles before scratch overlays k_lds

    // ---- epilogue: transpose O^T->O via per-wave LDS scratch, store bf16 ----
    float inv_l = 1.0f / l_run;
    char* scr = (char*)k_lds + wave * 2304;  // 32 rows x 72B, wave-private
#pragma unroll
    for (int ds = 0; ds < 4; ++ds) {
#pragma unroll
      for (int rp = 0; rp < 8; ++rp) {
        int r = rp * 2;
        int d_loc = (r & 3) + 8 * (r >> 2) + 4 * hi;  // even; pair covers d_loc, d_loc+1
        *(unsigned int*)(scr + l31 * 72 + ((d_loc >> 1) << 2)) =
            pk2(o_acc[ds][r] * inv_l, o_acc[ds][r + 1] * inv_l);
      }
      uint2 u0 = *(uint2*)(scr + l31 * 72 + hi * 32 + 0);
      uint2 u1 = *(uint2*)(scr + l31 * 72 + hi * 32 + 8);
      uint2 u2 = *(uint2*)(scr + l31 * 72 + hi * 32 + 16);
      uint2 u3 = *(uint2*)(scr + l31 * 72 + hi * 32 + 24);
      unsigned short* op = O + (size_t)qrow * 4096 + (h << 7) + ds * 32 + hi * 16;
      uint4 s0v; s0v.x = u0.x; s0v.y = u0.y; s0v.z = u1.x; s0v.w = u1.y;
      uint4 s1v; s1v.x = u2.x; s1v.y = u2.y; s1v.z = u3.x; s1v.w = u3.y;
      *(uint4*)(op) = s0v;
      *(uint4*)(op + 8) = s1v;
    }
  }
}

extern "C" void kernel_launch(void* const* d_in, const int* in_sizes, int n_in,
                              void* d_out, int out_size, void* d_ws, size_t ws_size,
                              hipStream_t stream) {
  const float* X  = (const float*)d_in[0];
  const float* Wq = (const float*)d_in[1];
  const float* Wk = (const float*)d_in[2];
  const float* Wv = (const float*)d_in[3];
  const float* Wo = (const float*)d_in[4];
  const int* pos  = (const int*)d_in[5];
  // d_in[6] attention_mask: causal tril -- enforced analytically in attn_kernel.

  const size_t MB = 1u << 20;
  char* w = (char*)d_ws;
  // Wkt/Wvt contiguous: a [1024][2048] bf16 block for the KV GEMM.
  unsigned short* Xb  = (unsigned short*)(w + 0 * MB);    // [4096][2048] 16MB
  unsigned short* Wqt = (unsigned short*)(w + 16 * MB);   // [4096][2048] 16MB
  unsigned short* Wkt = (unsigned short*)(w + 32 * MB);   // [512][2048]   2MB
  unsigned short* Wvt = (unsigned short*)(w + 34 * MB);   // [512][2048]   2MB
  unsigned short* Wot = (unsigned short*)(w + 36 * MB);   // [2048][4096] 16MB
  unsigned short* Qb  = (unsigned short*)(w + 52 * MB);   // [4096][4096] 32MB
  unsigned short* Kb  = (unsigned short*)(w + 84 * MB);   // [4096][512]   4MB
  unsigned short* Vtb = (unsigned short*)(w + 88 * MB);   // [4 hk][64 st][128 d][64 s] 4MB
  unsigned short* Ob  = (unsigned short*)(w + 92 * MB);   // [4096][4096] 32MB

  // 1) dtype conversion + weight transposes
  convert_kernel<<<8192, 256, 0, stream>>>(X, Xb, 4096 * 2048 / 4);
  transpose_convert_kernel<<<dim3(128, 64), dim3(32, 8), 0, stream>>>(Wq, Wqt, 2048, 4096);
  transpose_convert_kernel<<<dim3(16, 64),  dim3(32, 8), 0, stream>>>(Wk, Wkt, 2048, 512);
  transpose_convert_kernel<<<dim3(16, 64),  dim3(32, 8), 0, stream>>>(Wv, Wvt, 2048, 512);
  transpose_convert_kernel<<<dim3(64, 128), dim3(32, 8), 0, stream>>>(Wo, Wot, 4096, 2048);

  // 2a) Q projection: 256x256 tiles, grid exactly 256 blocks (one clean round)
  gemm_big_kernel<0, 256, 256><<<dim3(16, 16), 512, 0, stream>>>(Xb, Wqt, Qb, 4096, 4096, 2048);
  // 2b) KV projection: 128x128 tiles, grid 256 blocks, 3 blocks/CU (V written tiled)
  gemm_kv_kernel<<<dim3(8, 32), 256, 0, stream>>>(Xb, Wkt, Kb, Vtb, 2048);

  // 3) RoPE (Q gets 1/sqrt(128)*log2(e) folded in for exp2-domain softmax)
  rope_kernel<<<(4096 * 32 * 64) / 256, 256, 0, stream>>>(Qb, pos, 5, 4096, 0.12752792534390558f, 4096 * 32 * 64);
  rope_kernel<<<(4096 * 4 * 64) / 256,  256, 0, stream>>>(Kb, pos, 2, 512, 1.0f, 4096 * 4 * 64);

  // 4) causal flash attention (quad-buffer, one barrier per tile PAIR)
  attn_kernel<<<dim3(8, 32), 512, 0, stream>>>(Qb, Kb, Vtb, Ob);

  // 5) output projection -> fp32 d_out, 128x256 tiles (grid 8x32 = 256 blocks)
  gemm_big_kernel<1, 128, 256><<<dim3(8, 32), 512, 0, stream>>>(Ob, Wot, d_out, 4096, 2048, 4096);
}